// Round 3
// baseline (117.042 us; speedup 1.0000x reference)
//
#include <hip/hip_runtime.h>
#include <hip/hip_bf16.h>
#include <math.h>

#define NROW 4096
#define DIM  512
#define M2   8192                     // 2N rows
#define SELF_EXP 7.3890560989306495f  // exp(1/T) = exp(2)
#define NTILE 64                      // M2 / 128
#define NBLK  (NTILE * (NTILE + 1) / 2)   // 2080 upper-triangle tiles (8*260)
#define BK    32                      // K-step (elements)
#define NKS   (DIM / BK)              // 16 K-steps

typedef __hip_bfloat16 bf16;
typedef __attribute__((ext_vector_type(8))) short short8;   // 8 bf16 (4 VGPRs)
typedef __attribute__((ext_vector_type(4))) float f32x4;

// ---------------------------------------------------------------------------
// Kernel 1: fused row-normalize (x,y -> bf16 ns[8192][512]) + positive-pair
// cosine partial + rowsum zeroing + out zeroing (for finalize atomicAdd).
// ---------------------------------------------------------------------------
__global__ __launch_bounds__(256) void norm_pos_kernel(
    const float* __restrict__ x, const float* __restrict__ y,
    bf16* __restrict__ ns, float* __restrict__ pospart,
    float* __restrict__ rowsum, float* __restrict__ out)
{
    const int i = blockIdx.x;
    const int t = threadIdx.x;
    const float2 a = ((const float2*)(x + (size_t)i * DIM))[t];
    const float2 b = ((const float2*)(y + (size_t)i * DIM))[t];
    float sx = a.x * a.x + a.y * a.y;
    float sy = b.x * b.x + b.y * b.y;
    float dt = a.x * b.x + a.y * b.y;
    #pragma unroll
    for (int o = 1; o < 64; o <<= 1) {
        sx += __shfl_xor(sx, o);
        sy += __shfl_xor(sy, o);
        dt += __shfl_xor(dt, o);
    }
    __shared__ float rd[12];
    const int wid = t >> 6, lane = t & 63;
    if (lane == 0) { rd[wid] = sx; rd[4 + wid] = sy; rd[8 + wid] = dt; }
    __syncthreads();
    const float SX = rd[0] + rd[1] + rd[2] + rd[3];
    const float SY = rd[4] + rd[5] + rd[6] + rd[7];
    const float D  = rd[8] + rd[9] + rd[10] + rd[11];
    const float rnx = rsqrtf(SX), rny = rsqrtf(SY);

    bf16 a0 = __float2bfloat16(a.x * rnx), a1 = __float2bfloat16(a.y * rnx);
    bf16 b0 = __float2bfloat16(b.x * rny), b1 = __float2bfloat16(b.y * rny);
    ushort2 sa, sb;
    sa.x = *(unsigned short*)&a0; sa.y = *(unsigned short*)&a1;
    sb.x = *(unsigned short*)&b0; sb.y = *(unsigned short*)&b1;
    ((ushort2*)(void*)(ns + (size_t)i * DIM))[t] = sa;
    ((ushort2*)(void*)(ns + (size_t)(i + NROW) * DIM))[t] = sb;

    if (t == 0) pospart[i] = D * rnx * rny;
    if (t < 2)  rowsum[2 * i + t] = 0.f;
    if (i == 0 && t == 0) out[0] = 0.f;
}

// ---------------------------------------------------------------------------
// Kernel 2: symmetric Gram with fused exp(2*S) + row/col sums.
// 128x128 tile, BK=32, 32 KiB double-buffered LDS -> 5 blocks/CU (20 waves),
// counted vmcnt(4) true prefetch, both-sides slot swizzle (slot ^= (row>>1)&3,
// 2-way bank alias = free), XCD-chunked block swizzle. No setprio (m190).
// (r0-verified structure: 57.6 us, 0 bank conflicts; only change: 4->5 blk/CU)
// ---------------------------------------------------------------------------
__device__ __forceinline__ void stage_tiles(
    const char* nsb, short* lA, short* lB, int bi, int bj, int kk, int t)
{
    #pragma unroll
    for (int l = 0; l < 4; ++l) {                 // exactly 4 loads/thread
        const int chunk = l * 256 + t;            // 0..1023 16B chunks
        const int half  = chunk >> 9;             // 0:A 1:B (wave-uniform)
        const int o     = (chunk & 511) * 16;     // byte off within 8 KiB tile
        const int row   = o >> 6;                 // 64 B per LDS row
        const int slot  = (o >> 4) & 3;
        const int src   = (slot ^ ((row >> 1) & 3)) << 4;  // inverse swizzle
        const int grow  = (half ? bj : bi) * 128 + row;
        const char* gsrc = nsb + (size_t)grow * (DIM * 2) + kk * 2 + src;
        char* ldst = (char*)(half ? lB : lA) + o; // linear LDS dest
        __builtin_amdgcn_global_load_lds(
            (const __attribute__((address_space(1))) void*)gsrc,
            (__attribute__((address_space(3))) void*)ldst, 16, 0, 0);
    }
}

#define BARRIER() do { asm volatile("" ::: "memory");                          \
    __builtin_amdgcn_s_barrier(); asm volatile("" ::: "memory"); } while (0)

__global__ __launch_bounds__(256, 5) void gram_rowsum_kernel(
    const bf16* __restrict__ ns, float* __restrict__ rowsum)
{
    __shared__ short lA[2][128 * BK];   // 2 x 8 KiB
    __shared__ short lB[2][128 * BK];   // 2 x 8 KiB

    // XCD-chunked swizzle: 2080 % 8 == 0, each XCD gets 260 consecutive idx
    const int raw = blockIdx.x;
    const int idx = (raw & 7) * (NBLK / 8) + (raw >> 3);

    // decode upper-triangle tile index: idx = bj*(bj+1)/2 + bi, bi <= bj
    int bj = (int)floorf((sqrtf(8.0f * (float)idx + 1.0f) - 1.0f) * 0.5f);
    while ((bj + 1) * (bj + 2) / 2 <= idx) ++bj;
    while (bj * (bj + 1) / 2 > idx) --bj;
    const int bi = idx - bj * (bj + 1) / 2;

    const int t = threadIdx.x;
    const int lane = t & 63;
    const int l15  = lane & 15;
    const int wid  = t >> 6;
    const int wr = wid >> 1, wc = wid & 1;   // wave quadrant (64x64)

    f32x4 acc[4][4];
    #pragma unroll
    for (int m = 0; m < 4; ++m)
        #pragma unroll
        for (int n = 0; n < 4; ++n)
            acc[m][n] = (f32x4)0.f;

    const char* nsb = (const char*)ns;
    const int kb2 = (lane >> 4) * 16;        // byte offset of 8-elem fragment

    stage_tiles(nsb, lA[0], lB[0], bi, bj, 0, t);

    #pragma unroll
    for (int ks = 0; ks < NKS; ++ks) {
        const int cur = ks & 1;
        if (ks < NKS - 1) {
            // issue next K-step's 4 loads, then wait only for the PREVIOUS 4
            stage_tiles(nsb, lA[cur ^ 1], lB[cur ^ 1], bi, bj, (ks + 1) * BK, t);
            __builtin_amdgcn_sched_barrier(0);   // pin issues above the wait
            asm volatile("s_waitcnt vmcnt(4)" ::: "memory");
        } else {
            asm volatile("s_waitcnt vmcnt(0)" ::: "memory");
        }
        BARRIER();                               // all waves: cur buffer ready

        short8 af[4], bfr[4];
        #pragma unroll
        for (int m = 0; m < 4; ++m) {
            const int row = wr * 64 + m * 16 + l15;
            const int sw  = ((row >> 1) & 3) << 4;
            af[m] = *(const short8*)((const char*)lA[cur] + row * 64 + (kb2 ^ sw));
        }
        #pragma unroll
        for (int n = 0; n < 4; ++n) {
            const int row = wc * 64 + n * 16 + l15;
            const int sw  = ((row >> 1) & 3) << 4;
            bfr[n] = *(const short8*)((const char*)lB[cur] + row * 64 + (kb2 ^ sw));
        }
        #pragma unroll
        for (int m = 0; m < 4; ++m)
            #pragma unroll
            for (int n = 0; n < 4; ++n)
                acc[m][n] = __builtin_amdgcn_mfma_f32_16x16x32_bf16(
                    af[m], bfr[n], acc[m][n], 0, 0, 0);

        // all waves' ds_reads complete before MFMA (lgkm waits) -> after this
        // barrier it is safe for next iter to overwrite buf[cur]
        BARRIER();
    }

    // ---- epilogue: E = exp(2S); row sums always, col sums if off-diagonal --
    #pragma unroll
    for (int m = 0; m < 4; ++m)
        #pragma unroll
        for (int n = 0; n < 4; ++n)
            #pragma unroll
            for (int r = 0; r < 4; ++r)
                acc[m][n][r] = __expf(2.0f * acc[m][n][r]);

    // C/D layout: row = m*16 + (lane>>4)*4 + reg ; col = n*16 + (lane&15)
    #pragma unroll
    for (int m = 0; m < 4; ++m) {
        #pragma unroll
        for (int reg = 0; reg < 4; ++reg) {
            float p = acc[m][0][reg] + acc[m][1][reg] + acc[m][2][reg] + acc[m][3][reg];
            p += __shfl_xor(p, 1);
            p += __shfl_xor(p, 2);
            p += __shfl_xor(p, 4);
            p += __shfl_xor(p, 8);
            if (l15 == 0) {
                const int row = bi * 128 + wr * 64 + m * 16 + (lane >> 4) * 4 + reg;
                atomicAdd(&rowsum[row], p);
            }
        }
    }
    if (bi != bj) {
        #pragma unroll
        for (int n = 0; n < 4; ++n) {
            float p = 0.f;
            #pragma unroll
            for (int m = 0; m < 4; ++m)
                #pragma unroll
                for (int reg = 0; reg < 4; ++reg)
                    p += acc[m][n][reg];
            p += __shfl_xor(p, 16);
            p += __shfl_xor(p, 32);
            if (lane < 16) {
                const int col = bj * 128 + wc * 64 + n * 16 + lane;
                atomicAdd(&rowsum[col], p);
            }
        }
    }
}

// ---------------------------------------------------------------------------
// Kernel 3: finalize -> loss, parallel (32 blocks, atomicAdd into out)
// (saves ~12 us vs the single-block serial version: measured r0 vs r2)
// ---------------------------------------------------------------------------
__global__ __launch_bounds__(256) void finalize_kernel(
    const float* __restrict__ rowsum, const float* __restrict__ pospart,
    float* __restrict__ out)
{
    const int b = blockIdx.x, t = threadIdx.x;
    float s  = logf(rowsum[b * 256 + t] - SELF_EXP);
    float pp = (t < 128) ? pospart[b * 128 + t] : 0.f;
    #pragma unroll
    for (int o = 1; o < 64; o <<= 1) {
        s  += __shfl_xor(s, o);
        pp += __shfl_xor(pp, o);
    }
    __shared__ float rd[8];
    if ((t & 63) == 0) { rd[t >> 6] = s; rd[4 + (t >> 6)] = pp; }
    __syncthreads();
    if (t == 0) {
        const float ts = rd[0] + rd[1] + rd[2] + rd[3];
        const float tp = rd[4] + rd[5] + rd[6] + rd[7];
        atomicAdd(out, (ts - 4.0f * tp) / (float)M2);
    }
}

// ---------------------------------------------------------------------------
extern "C" void kernel_launch(void* const* d_in, const int* in_sizes, int n_in,
                              void* d_out, int out_size, void* d_ws, size_t ws_size,
                              hipStream_t stream)
{
    const float* x = (const float*)d_in[0];
    const float* y = (const float*)d_in[1];
    float* out = (float*)d_out;

    char* ws = (char*)d_ws;
    bf16*  ns      = (bf16*)ws;                               // 8 MiB
    float* rowsum  = (float*)(ws + (size_t)8 * 1024 * 1024);  // 32 KiB
    float* pospart = rowsum + M2;                             // 16 KiB

    norm_pos_kernel<<<NROW, 256, 0, stream>>>(x, y, ns, pospart, rowsum, out);

    gram_rowsum_kernel<<<NBLK, 256, 0, stream>>>(ns, rowsum);

    finalize_kernel<<<32, 256, 0, stream>>>(rowsum, pospart, out);
}

// Round 4
// 68.089 us; speedup vs baseline: 1.7190x; 1.7190x over previous
//
#include <hip/hip_runtime.h>
#include <hip/hip_bf16.h>
#include <math.h>

#define NROW 4096
#define DIM  512
#define M2   8192                     // 2N rows
#define SELF_EXP 7.3890560989306495f  // exp(1/T) = exp(2)
#define NTILE 64                      // M2 / 128
#define NBLK  (NTILE * (NTILE + 1) / 2)   // 2080 upper-triangle tiles (8*260)
#define BK    32                      // K-step (elements)
#define NKS   (DIM / BK)              // 16 K-steps

typedef __hip_bfloat16 bf16;
typedef __attribute__((ext_vector_type(8))) short short8;   // 8 bf16 (4 VGPRs)
typedef __attribute__((ext_vector_type(4))) float f32x4;

// ---------------------------------------------------------------------------
// Kernel 1: fused row-normalize (x,y -> bf16 ns[8192][512]) + positive-pair
// cosine partial + rowsum zeroing + out zeroing (for finalize atomicAdd).
// ---------------------------------------------------------------------------
__global__ __launch_bounds__(256) void norm_pos_kernel(
    const float* __restrict__ x, const float* __restrict__ y,
    bf16* __restrict__ ns, float* __restrict__ pospart,
    float* __restrict__ rowsum, float* __restrict__ out)
{
    const int i = blockIdx.x;
    const int t = threadIdx.x;
    const float2 a = ((const float2*)(x + (size_t)i * DIM))[t];
    const float2 b = ((const float2*)(y + (size_t)i * DIM))[t];
    float sx = a.x * a.x + a.y * a.y;
    float sy = b.x * b.x + b.y * b.y;
    float dt = a.x * b.x + a.y * b.y;
    #pragma unroll
    for (int o = 1; o < 64; o <<= 1) {
        sx += __shfl_xor(sx, o);
        sy += __shfl_xor(sy, o);
        dt += __shfl_xor(dt, o);
    }
    __shared__ float rd[12];
    const int wid = t >> 6, lane = t & 63;
    if (lane == 0) { rd[wid] = sx; rd[4 + wid] = sy; rd[8 + wid] = dt; }
    __syncthreads();
    const float SX = rd[0] + rd[1] + rd[2] + rd[3];
    const float SY = rd[4] + rd[5] + rd[6] + rd[7];
    const float D  = rd[8] + rd[9] + rd[10] + rd[11];
    const float rnx = rsqrtf(SX), rny = rsqrtf(SY);

    bf16 a0 = __float2bfloat16(a.x * rnx), a1 = __float2bfloat16(a.y * rnx);
    bf16 b0 = __float2bfloat16(b.x * rny), b1 = __float2bfloat16(b.y * rny);
    ushort2 sa, sb;
    sa.x = *(unsigned short*)&a0; sa.y = *(unsigned short*)&a1;
    sb.x = *(unsigned short*)&b0; sb.y = *(unsigned short*)&b1;
    ((ushort2*)(void*)(ns + (size_t)i * DIM))[t] = sa;
    ((ushort2*)(void*)(ns + (size_t)(i + NROW) * DIM))[t] = sb;

    if (t == 0) pospart[i] = D * rnx * rny;
    if (t < 2)  rowsum[2 * i + t] = 0.f;
    if (i == 0 && t == 0) out[0] = 0.f;
}

// ---------------------------------------------------------------------------
// Kernel 2: symmetric Gram with fused exp(2*S) + row/col sums.
// 128x128 tile, BK=32, 32 KiB double-buffered LDS -> 4 blocks/CU (16 waves),
// counted vmcnt(4) true prefetch, both-sides slot swizzle (slot ^= (row>>1)&3,
// 2-way bank alias = free), XCD-chunked block swizzle. No setprio (m190).
// NOTE: __launch_bounds__(256,4) is load-bearing: (256,5) caps VGPR at 48 <
// the 64-VGPR accumulator -> scratch spills, 180 MB writes, 2x slower (R3).
// ---------------------------------------------------------------------------
__device__ __forceinline__ void stage_tiles(
    const char* nsb, short* lA, short* lB, int bi, int bj, int kk, int t)
{
    #pragma unroll
    for (int l = 0; l < 4; ++l) {                 // exactly 4 loads/thread
        const int chunk = l * 256 + t;            // 0..1023 16B chunks
        const int half  = chunk >> 9;             // 0:A 1:B (wave-uniform)
        const int o     = (chunk & 511) * 16;     // byte off within 8 KiB tile
        const int row   = o >> 6;                 // 64 B per LDS row
        const int slot  = (o >> 4) & 3;
        const int src   = (slot ^ ((row >> 1) & 3)) << 4;  // inverse swizzle
        const int grow  = (half ? bj : bi) * 128 + row;
        const char* gsrc = nsb + (size_t)grow * (DIM * 2) + kk * 2 + src;
        char* ldst = (char*)(half ? lB : lA) + o; // linear LDS dest
        __builtin_amdgcn_global_load_lds(
            (const __attribute__((address_space(1))) void*)gsrc,
            (__attribute__((address_space(3))) void*)ldst, 16, 0, 0);
    }
}

#define BARRIER() do { asm volatile("" ::: "memory");                          \
    __builtin_amdgcn_s_barrier(); asm volatile("" ::: "memory"); } while (0)

__global__ __launch_bounds__(256, 4) void gram_rowsum_kernel(
    const bf16* __restrict__ ns, float* __restrict__ rowsum)
{
    __shared__ short lA[2][128 * BK];   // 2 x 8 KiB
    __shared__ short lB[2][128 * BK];   // 2 x 8 KiB

    // XCD-chunked swizzle: 2080 % 8 == 0, each XCD gets 260 consecutive idx
    const int raw = blockIdx.x;
    const int idx = (raw & 7) * (NBLK / 8) + (raw >> 3);

    // decode upper-triangle tile index: idx = bj*(bj+1)/2 + bi, bi <= bj
    int bj = (int)floorf((sqrtf(8.0f * (float)idx + 1.0f) - 1.0f) * 0.5f);
    while ((bj + 1) * (bj + 2) / 2 <= idx) ++bj;
    while (bj * (bj + 1) / 2 > idx) --bj;
    const int bi = idx - bj * (bj + 1) / 2;

    const int t = threadIdx.x;
    const int lane = t & 63;
    const int l15  = lane & 15;
    const int wid  = t >> 6;
    const int wr = wid >> 1, wc = wid & 1;   // wave quadrant (64x64)

    f32x4 acc[4][4];
    #pragma unroll
    for (int m = 0; m < 4; ++m)
        #pragma unroll
        for (int n = 0; n < 4; ++n)
            acc[m][n] = (f32x4)0.f;

    const char* nsb = (const char*)ns;
    const int kb2 = (lane >> 4) * 16;        // byte offset of 8-elem fragment

    stage_tiles(nsb, lA[0], lB[0], bi, bj, 0, t);

    #pragma unroll
    for (int ks = 0; ks < NKS; ++ks) {
        const int cur = ks & 1;
        if (ks < NKS - 1) {
            // issue next K-step's 4 loads, then wait only for the PREVIOUS 4
            stage_tiles(nsb, lA[cur ^ 1], lB[cur ^ 1], bi, bj, (ks + 1) * BK, t);
            __builtin_amdgcn_sched_barrier(0);   // pin issues above the wait
            asm volatile("s_waitcnt vmcnt(4)" ::: "memory");
        } else {
            asm volatile("s_waitcnt vmcnt(0)" ::: "memory");
        }
        BARRIER();                               // all waves: cur buffer ready

        short8 af[4], bfr[4];
        #pragma unroll
        for (int m = 0; m < 4; ++m) {
            const int row = wr * 64 + m * 16 + l15;
            const int sw  = ((row >> 1) & 3) << 4;
            af[m] = *(const short8*)((const char*)lA[cur] + row * 64 + (kb2 ^ sw));
        }
        #pragma unroll
        for (int n = 0; n < 4; ++n) {
            const int row = wc * 64 + n * 16 + l15;
            const int sw  = ((row >> 1) & 3) << 4;
            bfr[n] = *(const short8*)((const char*)lB[cur] + row * 64 + (kb2 ^ sw));
        }
        #pragma unroll
        for (int m = 0; m < 4; ++m)
            #pragma unroll
            for (int n = 0; n < 4; ++n)
                acc[m][n] = __builtin_amdgcn_mfma_f32_16x16x32_bf16(
                    af[m], bfr[n], acc[m][n], 0, 0, 0);

        // all waves' ds_reads complete before MFMA (lgkm waits) -> after this
        // barrier it is safe for next iter to overwrite buf[cur]
        BARRIER();
    }

    // ---- epilogue: E = exp(2S); row sums always, col sums if off-diagonal --
    #pragma unroll
    for (int m = 0; m < 4; ++m)
        #pragma unroll
        for (int n = 0; n < 4; ++n)
            #pragma unroll
            for (int r = 0; r < 4; ++r)
                acc[m][n][r] = __expf(2.0f * acc[m][n][r]);

    // C/D layout: row = m*16 + (lane>>4)*4 + reg ; col = n*16 + (lane&15)
    #pragma unroll
    for (int m = 0; m < 4; ++m) {
        #pragma unroll
        for (int reg = 0; reg < 4; ++reg) {
            float p = acc[m][0][reg] + acc[m][1][reg] + acc[m][2][reg] + acc[m][3][reg];
            p += __shfl_xor(p, 1);
            p += __shfl_xor(p, 2);
            p += __shfl_xor(p, 4);
            p += __shfl_xor(p, 8);
            if (l15 == 0) {
                const int row = bi * 128 + wr * 64 + m * 16 + (lane >> 4) * 4 + reg;
                atomicAdd(&rowsum[row], p);
            }
        }
    }
    if (bi != bj) {
        #pragma unroll
        for (int n = 0; n < 4; ++n) {
            float p = 0.f;
            #pragma unroll
            for (int m = 0; m < 4; ++m)
                #pragma unroll
                for (int reg = 0; reg < 4; ++reg)
                    p += acc[m][n][reg];
            p += __shfl_xor(p, 16);
            p += __shfl_xor(p, 32);
            if (lane < 16) {
                const int col = bj * 128 + wc * 64 + n * 16 + lane;
                atomicAdd(&rowsum[col], p);
            }
        }
    }
}

// ---------------------------------------------------------------------------
// Kernel 3: finalize -> loss, parallel (32 blocks, atomicAdd into out)
// (saves ~12 us vs the single-block serial version: measured r0 vs r2)
// ---------------------------------------------------------------------------
__global__ __launch_bounds__(256) void finalize_kernel(
    const float* __restrict__ rowsum, const float* __restrict__ pospart,
    float* __restrict__ out)
{
    const int b = blockIdx.x, t = threadIdx.x;
    float s  = logf(rowsum[b * 256 + t] - SELF_EXP);
    float pp = (t < 128) ? pospart[b * 128 + t] : 0.f;
    #pragma unroll
    for (int o = 1; o < 64; o <<= 1) {
        s  += __shfl_xor(s, o);
        pp += __shfl_xor(pp, o);
    }
    __shared__ float rd[8];
    if ((t & 63) == 0) { rd[t >> 6] = s; rd[4 + (t >> 6)] = pp; }
    __syncthreads();
    if (t == 0) {
        const float ts = rd[0] + rd[1] + rd[2] + rd[3];
        const float tp = rd[4] + rd[5] + rd[6] + rd[7];
        atomicAdd(out, (ts - 4.0f * tp) / (float)M2);
    }
}

// ---------------------------------------------------------------------------
extern "C" void kernel_launch(void* const* d_in, const int* in_sizes, int n_in,
                              void* d_out, int out_size, void* d_ws, size_t ws_size,
                              hipStream_t stream)
{
    const float* x = (const float*)d_in[0];
    const float* y = (const float*)d_in[1];
    float* out = (float*)d_out;

    char* ws = (char*)d_ws;
    bf16*  ns      = (bf16*)ws;                               // 8 MiB
    float* rowsum  = (float*)(ws + (size_t)8 * 1024 * 1024);  // 32 KiB
    float* pospart = rowsum + M2;                             // 16 KiB

    norm_pos_kernel<<<NROW, 256, 0, stream>>>(x, y, ns, pospart, rowsum, out);

    gram_rowsum_kernel<<<NBLK, 256, 0, stream>>>(ns, rowsum);

    finalize_kernel<<<32, 256, 0, stream>>>(rowsum, pospart, out);
}

// Round 5
// 47.675 us; speedup vs baseline: 2.4550x; 1.4282x over previous
//
#include <hip/hip_runtime.h>
#include <hip/hip_bf16.h>
#include <hip/hip_fp8.h>
#include <math.h>

#define NROW 4096
#define DIM  512
#define M2   8192                     // 2N rows
#define SELF_EXP 7.3890560989306495f  // exp(1/T) = exp(2)
#define NTILE 64                      // M2 / 128
#define NBLK  (NTILE * (NTILE + 1) / 2)   // 2080 upper-triangle tiles (8*260)
#define BK    64                      // K-step (fp8 elements) -> 64 B rows
#define NKS   (DIM / BK)              // 8 K-steps (halved vs bf16)

typedef __attribute__((ext_vector_type(2))) long l64x2;     // 16 B = 2 fp8 frags
typedef __attribute__((ext_vector_type(4))) float f32x4;

// ---------------------------------------------------------------------------
// Kernel 1: fused row-normalize (x,y -> fp8 e4m3 ns[8192][512]) + positive-
// pair cosine partial (EXACT fp32 path) + rowsum zeroing + out zeroing.
// ---------------------------------------------------------------------------
__global__ __launch_bounds__(256) void norm_pos_kernel(
    const float* __restrict__ x, const float* __restrict__ y,
    unsigned char* __restrict__ ns, float* __restrict__ pospart,
    float* __restrict__ rowsum, float* __restrict__ out)
{
    const int i = blockIdx.x;
    const int t = threadIdx.x;
    const float2 a = ((const float2*)(x + (size_t)i * DIM))[t];
    const float2 b = ((const float2*)(y + (size_t)i * DIM))[t];
    float sx = a.x * a.x + a.y * a.y;
    float sy = b.x * b.x + b.y * b.y;
    float dt = a.x * b.x + a.y * b.y;
    #pragma unroll
    for (int o = 1; o < 64; o <<= 1) {
        sx += __shfl_xor(sx, o);
        sy += __shfl_xor(sy, o);
        dt += __shfl_xor(dt, o);
    }
    __shared__ float rd[12];
    const int wid = t >> 6, lane = t & 63;
    if (lane == 0) { rd[wid] = sx; rd[4 + wid] = sy; rd[8 + wid] = dt; }
    __syncthreads();
    const float SX = rd[0] + rd[1] + rd[2] + rd[3];
    const float SY = rd[4] + rd[5] + rd[6] + rd[7];
    const float D  = rd[8] + rd[9] + rd[10] + rd[11];
    const float rnx = rsqrtf(SX), rny = rsqrtf(SY);

    __hip_fp8_e4m3 qa0(a.x * rnx), qa1(a.y * rnx);
    __hip_fp8_e4m3 qb0(b.x * rny), qb1(b.y * rny);
    uchar2 ua, ub;
    ua.x = (unsigned char)qa0.__x; ua.y = (unsigned char)qa1.__x;
    ub.x = (unsigned char)qb0.__x; ub.y = (unsigned char)qb1.__x;
    ((uchar2*)(void*)(ns + (size_t)i * DIM))[t] = ua;
    ((uchar2*)(void*)(ns + (size_t)(i + NROW) * DIM))[t] = ub;

    if (t == 0) pospart[i] = D * rnx * rny;
    if (t < 2)  rowsum[2 * i + t] = 0.f;
    if (i == 0 && t == 0) out[0] = 0.f;
}

// ---------------------------------------------------------------------------
// Kernel 2: symmetric Gram (fp8 e4m3 inputs) with fused exp(2*S) + row/col
// sums. Same verified skeleton as the 57.2us bf16 kernel: 128x128 tile,
// 32 KiB double-buffered LDS (4 blk/CU, 16 waves), counted vmcnt(4) prefetch,
// both-sides slot swizzle (slot ^= (row>>1)&3, 2-way alias = free),
// XCD-chunked block swizzle. fp8 + BK=64 keeps the LDS byte layout identical
// (64-B rows, 8 KiB/tile, 4 loads/thread) but halves NKS 16->8: barriers,
// staging and ds_reads halve; MFMA count unchanged.
// k-permutation inside the 64-B row is harmless: A and B use identical load
// code, so any bijective k-relabeling cancels in the symmetric dot product.
// NOTE: __launch_bounds__(256,4) is load-bearing (R3: (256,5) -> spills).
// ---------------------------------------------------------------------------
__device__ __forceinline__ void stage_tiles(
    const char* nsb, char* lA, char* lB, int bi, int bj, int koff, int t)
{
    #pragma unroll
    for (int l = 0; l < 4; ++l) {                 // exactly 4 loads/thread
        const int chunk = l * 256 + t;            // 0..1023 16B chunks
        const int half  = chunk >> 9;             // 0:A 1:B (wave-uniform)
        const int o     = (chunk & 511) * 16;     // byte off within 8 KiB tile
        const int row   = o >> 6;                 // 64 B per LDS row
        const int slot  = (o >> 4) & 3;
        const int src   = (slot ^ ((row >> 1) & 3)) << 4;  // inverse swizzle
        const int grow  = (half ? bj : bi) * 128 + row;
        const char* gsrc = nsb + (size_t)grow * DIM + koff + src;  // 512 B rows
        char* ldst = (half ? lB : lA) + o;        // linear LDS dest
        __builtin_amdgcn_global_load_lds(
            (const __attribute__((address_space(1))) void*)gsrc,
            (__attribute__((address_space(3))) void*)ldst, 16, 0, 0);
    }
}

#define BARRIER() do { asm volatile("" ::: "memory");                          \
    __builtin_amdgcn_s_barrier(); asm volatile("" ::: "memory"); } while (0)

__global__ __launch_bounds__(256, 4) void gram_rowsum_kernel(
    const unsigned char* __restrict__ ns, float* __restrict__ rowsum)
{
    __shared__ char lA[2][128 * BK];   // 2 x 8 KiB (fp8)
    __shared__ char lB[2][128 * BK];   // 2 x 8 KiB

    // XCD-chunked swizzle: 2080 % 8 == 0, each XCD gets 260 consecutive idx
    const int raw = blockIdx.x;
    const int idx = (raw & 7) * (NBLK / 8) + (raw >> 3);

    // decode upper-triangle tile index: idx = bj*(bj+1)/2 + bi, bi <= bj
    int bj = (int)floorf((sqrtf(8.0f * (float)idx + 1.0f) - 1.0f) * 0.5f);
    while ((bj + 1) * (bj + 2) / 2 <= idx) ++bj;
    while (bj * (bj + 1) / 2 > idx) --bj;
    const int bi = idx - bj * (bj + 1) / 2;

    const int t = threadIdx.x;
    const int lane = t & 63;
    const int l15  = lane & 15;
    const int wid  = t >> 6;
    const int wr = wid >> 1, wc = wid & 1;   // wave quadrant (64x64)

    f32x4 acc[4][4];
    #pragma unroll
    for (int m = 0; m < 4; ++m)
        #pragma unroll
        for (int n = 0; n < 4; ++n)
            acc[m][n] = (f32x4)0.f;

    const char* nsb = (const char*)ns;
    const int kb2 = (lane >> 4) * 16;        // byte offset of 16B k-slot

    stage_tiles(nsb, lA[0], lB[0], bi, bj, 0, t);

    #pragma unroll
    for (int ks = 0; ks < NKS; ++ks) {
        const int cur = ks & 1;
        if (ks < NKS - 1) {
            // issue next K-step's 4 loads, then wait only for the PREVIOUS 4
            stage_tiles(nsb, lA[cur ^ 1], lB[cur ^ 1], bi, bj, (ks + 1) * BK, t);
            __builtin_amdgcn_sched_barrier(0);   // pin issues above the wait
            asm volatile("s_waitcnt vmcnt(4)" ::: "memory");
        } else {
            asm volatile("s_waitcnt vmcnt(0)" ::: "memory");
        }
        BARRIER();                               // all waves: cur buffer ready

        l64x2 av[4], bv[4];
        #pragma unroll
        for (int m = 0; m < 4; ++m) {
            const int row = wr * 64 + m * 16 + l15;
            const int sw  = ((row >> 1) & 3) << 4;
            av[m] = *(const l64x2*)((const char*)lA[cur] + row * 64 + (kb2 ^ sw));
        }
        #pragma unroll
        for (int n = 0; n < 4; ++n) {
            const int row = wc * 64 + n * 16 + l15;
            const int sw  = ((row >> 1) & 3) << 4;
            bv[n] = *(const l64x2*)((const char*)lB[cur] + row * 64 + (kb2 ^ sw));
        }
        // K=64 per step: two chained fp8 MFMAs (lo/hi 8-byte halves)
        #pragma unroll
        for (int m = 0; m < 4; ++m)
            #pragma unroll
            for (int n = 0; n < 4; ++n) {
                acc[m][n] = __builtin_amdgcn_mfma_f32_16x16x32_fp8_fp8(
                    av[m].x, bv[n].x, acc[m][n], 0, 0, 0);
                acc[m][n] = __builtin_amdgcn_mfma_f32_16x16x32_fp8_fp8(
                    av[m].y, bv[n].y, acc[m][n], 0, 0, 0);
            }

        BARRIER();
    }

    // ---- epilogue: E = exp(2S); row sums always, col sums if off-diagonal --
    #pragma unroll
    for (int m = 0; m < 4; ++m)
        #pragma unroll
        for (int n = 0; n < 4; ++n)
            #pragma unroll
            for (int r = 0; r < 4; ++r)
                acc[m][n][r] = __expf(2.0f * acc[m][n][r]);

    // C/D layout (dtype-independent): row = m*16+(lane>>4)*4+reg ; col = n*16+(lane&15)
    #pragma unroll
    for (int m = 0; m < 4; ++m) {
        #pragma unroll
        for (int reg = 0; reg < 4; ++reg) {
            float p = acc[m][0][reg] + acc[m][1][reg] + acc[m][2][reg] + acc[m][3][reg];
            p += __shfl_xor(p, 1);
            p += __shfl_xor(p, 2);
            p += __shfl_xor(p, 4);
            p += __shfl_xor(p, 8);
            if (l15 == 0) {
                const int row = bi * 128 + wr * 64 + m * 16 + (lane >> 4) * 4 + reg;
                atomicAdd(&rowsum[row], p);
            }
        }
    }
    if (bi != bj) {
        #pragma unroll
        for (int n = 0; n < 4; ++n) {
            float p = 0.f;
            #pragma unroll
            for (int m = 0; m < 4; ++m)
                #pragma unroll
                for (int reg = 0; reg < 4; ++reg)
                    p += acc[m][n][reg];
            p += __shfl_xor(p, 16);
            p += __shfl_xor(p, 32);
            if (lane < 16) {
                const int col = bj * 128 + wc * 64 + n * 16 + lane;
                atomicAdd(&rowsum[col], p);
            }
        }
    }
}

// ---------------------------------------------------------------------------
// Kernel 3: finalize -> loss, parallel (32 blocks, atomicAdd into out)
// ---------------------------------------------------------------------------
__global__ __launch_bounds__(256) void finalize_kernel(
    const float* __restrict__ rowsum, const float* __restrict__ pospart,
    float* __restrict__ out)
{
    const int b = blockIdx.x, t = threadIdx.x;
    float s  = logf(rowsum[b * 256 + t] - SELF_EXP);
    float pp = (t < 128) ? pospart[b * 128 + t] : 0.f;
    #pragma unroll
    for (int o = 1; o < 64; o <<= 1) {
        s  += __shfl_xor(s, o);
        pp += __shfl_xor(pp, o);
    }
    __shared__ float rd[8];
    if ((t & 63) == 0) { rd[t >> 6] = s; rd[4 + (t >> 6)] = pp; }
    __syncthreads();
    if (t == 0) {
        const float ts = rd[0] + rd[1] + rd[2] + rd[3];
        const float tp = rd[4] + rd[5] + rd[6] + rd[7];
        atomicAdd(out, (ts - 4.0f * tp) / (float)M2);
    }
}

// ---------------------------------------------------------------------------
extern "C" void kernel_launch(void* const* d_in, const int* in_sizes, int n_in,
                              void* d_out, int out_size, void* d_ws, size_t ws_size,
                              hipStream_t stream)
{
    const float* x = (const float*)d_in[0];
    const float* y = (const float*)d_in[1];
    float* out = (float*)d_out;

    char* ws = (char*)d_ws;
    unsigned char* ns = (unsigned char*)ws;                   // 4 MiB (fp8)
    float* rowsum  = (float*)(ws + (size_t)4 * 1024 * 1024);  // 32 KiB
    float* pospart = rowsum + M2;                             // 16 KiB

    norm_pos_kernel<<<NROW, 256, 0, stream>>>(x, y, ns, pospart, rowsum, out);

    gram_rowsum_kernel<<<NBLK, 256, 0, stream>>>(ns, rowsum);

    finalize_kernel<<<32, 256, 0, stream>>>(rowsum, pospart, out);
}